// Round 13
// baseline (90.276 us; speedup 1.0000x reference)
//
#include <hip/hip_runtime.h>
#include <math.h>

#define NW 192
#define Wt 193
#define CHUNK 48           // k2 per block
#define NMAIN 768          // 192 k1 x 4 chunks; 512 thr -> exactly 3 blocks/CU

// cos(2*pi*num*rcpden) via HW cos (input in revolutions)
__device__ __forceinline__ float cos_revr(float num, float rcpden) {
    float rev = num * rcpden;
    rev = __builtin_amdgcn_fractf(rev);
    return __builtin_amdgcn_cosf(rev);
}

// wave-uniform broadcast from a compile-time lane via v_readlane
__device__ __forceinline__ float rdlane(float v, int l) {
    return __builtin_bit_cast(float,
        __builtin_amdgcn_readlane(__builtin_bit_cast(int, v), l));
}

// ---------------- k_fused v13: v11 + register-resident x (readlane) ----------------
// Block b: k1 = b>>2, chunk c = b&3 (k2 in [48c,48c+48)). 512 thr = 8 waves.
// LDS: win 13KB + part 16KB = 29.4KB (xls DELETED) -> 3 blocks/CU, 24 waves.
// A: win[p][c] coalesced into LDS (lane = c).                       [v11]
// B: lane = p (<48): win rows per-lane LDS b128; M rows wave-uniform s_load;
//    x[p][jb..jb+8) stays in accj[8] REGISTERS (no xls write).      [v11->new]
// Seeds: d_k = (cos(k1 th)*P[i][j]) * cos(k th) folded into seeds.  [v11]
// D: xs[jl] = readlane(accj[jl], k2i) — same-wave register broadcast,
//    no LDS read, no lgkmcnt wait, one barrier fewer.               [new, v10-proven mapping]
__global__ __launch_bounds__(512, 4) void k_fused(const float* __restrict__ grid,
                                                  const float* __restrict__ Mw,
                                                  const float* __restrict__ P,
                                                  float* __restrict__ out) {
    __shared__ float win[CHUNK * 68];   // [p][c], stride 68
    __shared__ float part[4096];        // [w 8][k2slot 8][i 64] = 16 KB

    int bx = blockIdx.x;
    int k1  = bx >> 2;                  // 0..191
    int k2s = (bx & 3) * CHUNK;         // 0,48,96,144
    int t = threadIdx.x;
    int lane = t & 63;
    int w = __builtin_amdgcn_readfirstlane(t >> 6);   // 0..7
    int jb = w * 8;

    // ---- Phase A: window averages, coalesced (lane = channel c) ----
    {
        int c = lane;
        const float* gb  = grid + ((size_t)k1 * Wt + k2s) * 64 + c;
        const float* gb1 = gb + (size_t)Wt * 64;
        #pragma unroll
        for (int r = 0; r < 6; ++r) {
            int p = w * 6 + r;          // 8 waves x 6 = 48 positions
            float s = gb[p * 64] + gb[(p + 1) * 64]
                    + gb1[p * 64] + gb1[(p + 1) * 64];
            win[p * 68 + c] = 0.25f * s;
        }
    }
    __syncthreads();                    // sync1: win visible

    // ---- Phase B: x[p][jb..jb+8) in regs (lane = p; M via s_load) ----
    float accj[8];
    #pragma unroll
    for (int r = 0; r < 8; ++r) accj[r] = 0.f;
    if (lane < CHUNK) {
        #pragma unroll
        for (int q4 = 0; q4 < 4; ++q4) {
            float4 wv0 = *(const float4*)&win[lane * 68 + q4 * 16];
            float4 wv1 = *(const float4*)&win[lane * 68 + q4 * 16 + 4];
            float4 wv2 = *(const float4*)&win[lane * 68 + q4 * 16 + 8];
            float4 wv3 = *(const float4*)&win[lane * 68 + q4 * 16 + 12];
            #pragma unroll
            for (int r = 0; r < 8; ++r) {
                // wave-uniform address -> s_load_dwordx4 (scalar cache)
                const float4* mr = (const float4*)&Mw[(jb + r) * 64 + q4 * 16];
                float4 m0 = mr[0], m1 = mr[1], m2 = mr[2], m3 = mr[3];
                accj[r] += wv0.x * m0.x + wv0.y * m0.y + wv0.z * m0.z + wv0.w * m0.w
                         + wv1.x * m1.x + wv1.y * m1.y + wv1.z * m1.z + wv1.w * m1.w
                         + wv2.x * m2.x + wv2.y * m2.y + wv2.z * m2.z + wv2.w * m2.w
                         + wv3.x * m3.x + wv3.y * m3.y + wv3.z * m3.z + wv3.w * m3.w;
            }
        }
    }
    // accj stays in registers: wave w's lane p holds x[p][jb..jb+8).
    // Phase D (same wave) broadcasts lane k2i via readlane — no barrier needed.

    // ---- Seeds: d_k[jl] = c1v*cos(k*theta); c1v folded into seeds ----
    float A[8], ce[8], co[8];
    {
        float4 pr0 = *(const float4*)&P[lane * 64 + jb];
        float4 pr1 = *(const float4*)&P[lane * 64 + jb + 4];
        float pv[8] = {pr0.x, pr0.y, pr0.z, pr0.w, pr1.x, pr1.y, pr1.z, pr1.w};
        float k1f = (float)k1, k2f = (float)k2s;
        #pragma unroll
        for (int jl = 0; jl < 8; ++jl) {
            float T  = (float)(lane * 64 + jb + jl + 2);
            float rT = __builtin_amdgcn_rcpf(T);
            A[jl]    = 2.0f * cos_revr(1.0f, rT);
            float c1 = cos_revr(k1f, rT) * pv[jl];
            ce[jl]   = cos_revr(k2f, rT) * c1;          // d_{k2s}
            co[jl]   = cos_revr(k2f - 1.0f, rT) * c1;   // d_{k2s-1}
        }
    }

    // ---- Phase D: 6 subs x 8 k2 steps; xs via same-wave readlane ----
    #pragma unroll
    for (int sub = 0; sub < 6; ++sub) {
        #pragma unroll
        for (int m = 0; m < 4; ++m) {
            {   // even step: current = ce, advance co
                int s = 2 * m;
                int k2i = sub * 8 + s;                  // compile-time lane idx
                float pa = 0.f, pb = 0.f;               // two 4-deep chains
                #pragma unroll
                for (int jl = 0; jl < 4; ++jl) {
                    float xs = rdlane(accj[jl], k2i);
                    pa     = fmaf(xs, ce[jl], pa);
                    co[jl] = fmaf(A[jl], ce[jl], -co[jl]);
                }
                #pragma unroll
                for (int jl = 4; jl < 8; ++jl) {
                    float xs = rdlane(accj[jl], k2i);
                    pb     = fmaf(xs, ce[jl], pb);
                    co[jl] = fmaf(A[jl], ce[jl], -co[jl]);
                }
                part[(w * 8 + s) * 64 + lane] = pa + pb;
            }
            {   // odd step: current = co, advance ce
                int s = 2 * m + 1;
                int k2i = sub * 8 + s;
                float pa = 0.f, pb = 0.f;
                #pragma unroll
                for (int jl = 0; jl < 4; ++jl) {
                    float xs = rdlane(accj[jl], k2i);
                    pa     = fmaf(xs, co[jl], pa);
                    ce[jl] = fmaf(A[jl], co[jl], -ce[jl]);
                }
                #pragma unroll
                for (int jl = 4; jl < 8; ++jl) {
                    float xs = rdlane(accj[jl], k2i);
                    pb     = fmaf(xs, co[jl], pb);
                    ce[jl] = fmaf(A[jl], co[jl], -ce[jl]);
                }
                part[(w * 8 + s) * 64 + lane] = pa + pb;
            }
        }
        __syncthreads();                // all 8 wave-partial slices written
        {   // reduce 8 wave-partials; 512 thr = one (k2slot,i) each; coalesced
            float r = part[t];
            #pragma unroll
            for (int ww = 1; ww < 8; ++ww) r += part[ww * 512 + t];
            out[((size_t)k1 * NW + (k2s + sub * 8 + (t >> 6))) * 64 + (t & 63)] = r;
        }
        __syncthreads();                // part reusable next sub
    }
}

extern "C" void kernel_launch(void* const* d_in, const int* in_sizes, int n_in,
                              void* d_out, int out_size, void* d_ws, size_t ws_size,
                              hipStream_t stream) {
    const float* grid = (const float*)d_in[0];   // [193,193,64]
    const float* Mw   = (const float*)d_in[1];   // [64,64]
    const float* P    = (const float*)d_in[2];   // [64,64]
    float* out = (float*)d_out;                  // [36864,64]
    (void)d_ws; (void)ws_size;                   // workspace unused

    k_fused<<<NMAIN, 512, 0, stream>>>(grid, Mw, P, out);
}